// Round 6
// baseline (484.677 us; speedup 1.0000x reference)
//
#include <hip/hip_runtime.h>
#include <hip/hip_cooperative_groups.h>

namespace cg = cooperative_groups;

typedef unsigned short ushort_t;
typedef __attribute__((ext_vector_type(8))) short shortx8;
typedef __attribute__((ext_vector_type(4))) float floatx4;
typedef __attribute__((ext_vector_type(2))) float floatx2;

#define NS 0.1f

__device__ __forceinline__ ushort_t f2bf_rne(float f) {
  union { float f; unsigned int u; } v; v.f = f;
  unsigned int r = v.u + 0x7FFFu + ((v.u >> 16) & 1u);
  return (ushort_t)(r >> 16);
}
// pack two f32 -> bf16x2 (round-half-up) in one v_perm: low16=bf(a), high16=bf(b)
__device__ __forceinline__ unsigned int pk2bf(float a, float b) {
  union { float f; unsigned int u; } x, y; x.f = a; y.f = b;
  return __builtin_amdgcn_perm(y.u + 0x8000u, x.u + 0x8000u, 0x07060302u);
}
__device__ __forceinline__ ushort_t f2bf_rhu(float f) {
  union { float f; unsigned int u; } v; v.f = f;
  return (ushort_t)((v.u + 0x8000u) >> 16);
}
__device__ __forceinline__ float lk(float x) { return fmaxf(x, NS * x); }
__device__ __forceinline__ floatx2 lk2(floatx2 v) {
  return __builtin_elementwise_max(v, v * (floatx2){NS, NS});
}

struct Prm {
  const float* fres; const float* coords; const float* W_emb;
  const float* W_e1; const float* b_e1; const float* W_e2; const float* b_e2;
  const float* W_inf; const float* b_inf; const float* W_h1; const float* b_h1;
  const float* W_h2; const float* b_h2;
  float* out; float* hA; float* hB; float* tib; float* tjf; float* mp0; float* mp1;
  ushort_t* wijf; ushort_t* we2f; ushort_t* wh1f; ushort_t* wh2f;
};

// proj epilogue store: ti plain [m][n<128]; tj fragment-linear for the edge phase
__device__ __forceinline__ void proj_store(const Prm& p, float v, int m, int n) {
  if (n < 128) {
    p.tib[(size_t)m * 128 + n] = v;
  } else {
    int k = n - 128, b = m >> 8, j = m & 255;
    int s = k >> 5, lg2 = (k >> 3) & 3, j8 = k & 7;
    p.tjf[((((size_t)(b * 4 + s)) * 256 + j) * 4 + lg2) * 8 + j8] = v;
  }
}

// ---------------- P0: weight prep to fragment-linear bf16 (grid-stride) ----------------
__device__ void phase_prep(const Prm& p) {
  for (int e = blockIdx.x * 256 + threadIdx.x; e < 98304; e += gridDim.x * 256) {
    int which, le;
    if (e < 32768) { which = 0; le = e; }
    else if (e < 49152) { which = 1; le = e - 32768; }
    else if (e < 81920) { which = 2; le = e - 49152; }
    else { which = 3; le = e - 81920; }
    const int NT = (which == 0) ? 16 : 8;
    int f = le >> 3, j = le & 7;
    int lane = f & 63, ft = f >> 6;
    int t = ft % NT, s = ft / NT;
    int n = t * 16 + (lane & 15), k = s * 32 + (lane >> 4) * 8 + j;
    float v; ushort_t* d;
    if (which == 0) { v = (n < 128) ? p.W_e1[k * 128 + n] : p.W_e1[(128 + k) * 128 + (n - 128)]; d = p.wijf; }
    else if (which == 1) { v = p.W_e2[k * 128 + n]; d = p.we2f; }
    else if (which == 2) { v = p.W_h1[k * 128 + n]; d = p.wh1f; }
    else { v = p.W_h2[k * 128 + n]; d = p.wh2f; }
    d[le] = f2bf_rne(v);
  }
}

// ---------------- P1: h0 = leaky(fres @ W_emb) + proj (grid-stride, 128 units) ----------------
__device__ void phase_h0proj(const Prm& p, char* smem) {
  ushort_t (*sH)[136] = (ushort_t(*)[136])smem;
  const int tid = threadIdx.x;
  const int w = tid >> 6, lane = tid & 63, l16 = lane & 15, lg = lane >> 4;
  for (int blk = blockIdx.x; blk < 128; blk += gridDim.x) {
    const int m0 = blk * 16;
    {
      const int row = tid >> 4, c0 = (tid & 15) * 8;
      const float* fr = p.fres + (size_t)(m0 + row) * 20;
      float a[8] = {0, 0, 0, 0, 0, 0, 0, 0};
      for (int k = 0; k < 20; ++k) {
        float fv = fr[k];
        float4 w0 = *(const float4*)(p.W_emb + k * 128 + c0);
        float4 w1 = *(const float4*)(p.W_emb + k * 128 + c0 + 4);
        a[0] += fv * w0.x; a[1] += fv * w0.y; a[2] += fv * w0.z; a[3] += fv * w0.w;
        a[4] += fv * w1.x; a[5] += fv * w1.y; a[6] += fv * w1.z; a[7] += fv * w1.w;
      }
#pragma unroll
      for (int x = 0; x < 8; ++x) a[x] = lk(a[x]);
      float* ho = p.hA + (size_t)(m0 + row) * 128 + c0;
      *(float4*)ho = (float4){a[0], a[1], a[2], a[3]};
      *(float4*)(ho + 4) = (float4){a[4], a[5], a[6], a[7]};
      unsigned int* sh = (unsigned int*)&sH[row][c0];
      sh[0] = pk2bf(a[0], a[1]); sh[1] = pk2bf(a[2], a[3]);
      sh[2] = pk2bf(a[4], a[5]); sh[3] = pk2bf(a[6], a[7]);
    }
    __syncthreads();
    floatx4 ap[4];
#pragma unroll
    for (int q = 0; q < 4; ++q) ap[q] = (floatx4){0.f, 0.f, 0.f, 0.f};
    const shortx8* Wp = (const shortx8*)p.wijf;
#pragma unroll
    for (int s = 0; s < 4; ++s) {
      shortx8 af = *(const shortx8*)&sH[l16][s * 32 + lg * 8];
#pragma unroll
      for (int q = 0; q < 4; ++q)
        ap[q] = __builtin_amdgcn_mfma_f32_16x16x32_bf16(af, Wp[(s * 16 + 4 * w + q) * 64 + lane], ap[q], 0, 0, 0);
    }
#pragma unroll
    for (int q = 0; q < 4; ++q) {
      const int n = (4 * w + q) * 16 + l16;
#pragma unroll
      for (int r = 0; r < 4; ++r) proj_store(p, ap[q][r], m0 + lg * 4 + r, n);
    }
    __syncthreads();
  }
}

// ---------------- P2/P4: edge phase, grid-stride over 4096 units, We2 staged once ----------------
__device__ void phase_edge(const Prm& p, char* smem) {
  const int tid = threadIdx.x;
  const int w = tid >> 6, lane = tid & 63, l16 = lane & 15, lg = lane >> 4;
  ushort_t* sW = (ushort_t*)smem;
  float* sTiP = (float*)(smem + 32768);
  float* sWd  = (float*)(smem + 33280);
  float* sD2  = (float*)(smem + 33792);
  float* sMp  = (float*)(smem + 34304);   // [4][128]
  {
    shortx8* dst = (shortx8*)sW;
    const shortx8* src = (const shortx8*)p.we2f;
#pragma unroll
    for (int r = 0; r < 8; ++r) dst[r * 256 + tid] = src[r * 256 + tid];
    if (tid < 128) sWd[tid] = p.W_e1[256 * 128 + tid];
  }
  const shortx8* sWf = (const shortx8*)sW;
  const int per = (4096 + gridDim.x - 1) / gridDim.x;

  for (int u = 0; u < per; ++u) {
    const int unit = blockIdx.x * per + u;
    if (unit >= 4096) break;
    const int b = unit >> 9, i = (unit >> 1) & 255, ch = unit & 1;
    __syncthreads();                       // protects staging (u=0) + prior unit's sMp reads
    if (tid < 128) {
      sTiP[tid] = p.tib[(size_t)(b * 256 + i) * 128 + tid] + p.b_e1[tid];
      const int j = ch * 128 + tid;
      float dx = p.coords[(size_t)(b * 256 + i) * 3 + 0] - p.coords[(size_t)(b * 256 + j) * 3 + 0];
      float dy = p.coords[(size_t)(b * 256 + i) * 3 + 1] - p.coords[(size_t)(b * 256 + j) * 3 + 1];
      float dz = p.coords[(size_t)(b * 256 + i) * 3 + 2] - p.coords[(size_t)(b * 256 + j) * 3 + 2];
      sD2[tid] = dx * dx + dy * dy + dz * dz;
    }
    floatx4 acc[2][8];
#pragma unroll
    for (int t = 0; t < 8; ++t) {
      float bv = p.b_e2[t * 16 + l16];
      acc[0][t] = (floatx4){bv, bv, bv, bv};
      acc[1][t] = acc[0][t];
    }
    __syncthreads();
    float d2a0 = sD2[w * 16 + l16], d2a1 = sD2[64 + w * 16 + l16];
#pragma unroll
    for (int s = 0; s < 4; ++s) {
      const int k0 = s * 32 + lg * 8;
      floatx2 p2[4], w2[4];
#pragma unroll
      for (int x = 0; x < 4; ++x) {
        p2[x] = *(const floatx2*)&sTiP[k0 + 2 * x];
        w2[x] = *(const floatx2*)&sWd[k0 + 2 * x];
      }
      shortx8 af[2];
#pragma unroll
      for (int c = 0; c < 2; ++c) {
        const int jr = ch * 128 + c * 64 + w * 16 + l16;
        const float* tb = p.tjf + (((size_t)(b * 4 + s) * 256 + jr) * 4 + lg) * 8;
        float4 t0 = *(const float4*)tb;
        float4 t1 = *(const float4*)(tb + 4);
        const float d2 = c ? d2a1 : d2a0;
        const floatx2 d2v = (floatx2){d2, d2};
        floatx2 pr0 = (floatx2){t0.x, t0.y} + (p2[0] + d2v * w2[0]);
        floatx2 pr1 = (floatx2){t0.z, t0.w} + (p2[1] + d2v * w2[1]);
        floatx2 pr2 = (floatx2){t1.x, t1.y} + (p2[2] + d2v * w2[2]);
        floatx2 pr3 = (floatx2){t1.z, t1.w} + (p2[3] + d2v * w2[3]);
        floatx2 l0 = lk2(pr0), l1 = lk2(pr1), l2 = lk2(pr2), l3 = lk2(pr3);
        union { shortx8 s8; unsigned int uu[4]; } A;
        A.uu[0] = pk2bf(l0.x, l0.y); A.uu[1] = pk2bf(l1.x, l1.y);
        A.uu[2] = pk2bf(l2.x, l2.y); A.uu[3] = pk2bf(l3.x, l3.y);
        af[c] = A.s8;
      }
#pragma unroll
      for (int tg = 0; tg < 2; ++tg) {
        shortx8 b0 = sWf[(s * 8 + tg * 4 + 0) * 64 + lane];
        shortx8 b1 = sWf[(s * 8 + tg * 4 + 1) * 64 + lane];
        shortx8 b2 = sWf[(s * 8 + tg * 4 + 2) * 64 + lane];
        shortx8 b3 = sWf[(s * 8 + tg * 4 + 3) * 64 + lane];
#pragma unroll
        for (int c = 0; c < 2; ++c) {
          acc[c][tg * 4 + 0] = __builtin_amdgcn_mfma_f32_16x16x32_bf16(af[c], b0, acc[c][tg * 4 + 0], 0, 0, 0);
          acc[c][tg * 4 + 1] = __builtin_amdgcn_mfma_f32_16x16x32_bf16(af[c], b1, acc[c][tg * 4 + 1], 0, 0, 0);
          acc[c][tg * 4 + 2] = __builtin_amdgcn_mfma_f32_16x16x32_bf16(af[c], b2, acc[c][tg * 4 + 2], 0, 0, 0);
          acc[c][tg * 4 + 3] = __builtin_amdgcn_mfma_f32_16x16x32_bf16(af[c], b3, acc[c][tg * 4 + 3], 0, 0, 0);
        }
      }
    }
    // packed epilogue: leaky, gate dot, masked weighted reduction
    float winfv[8];
#pragma unroll
    for (int t = 0; t < 8; ++t) winfv[t] = p.W_inf[t * 16 + l16];
    const float binf = p.b_inf[0];
    floatx2 mpp[8];
#pragma unroll
    for (int t = 0; t < 8; ++t) mpp[t] = (floatx2){0.f, 0.f};
#pragma unroll
    for (int c = 0; c < 2; ++c) {
#pragma unroll
      for (int t = 0; t < 8; ++t) {
        floatx2 v0 = lk2((floatx2){acc[c][t][0], acc[c][t][1]});
        floatx2 v1 = lk2((floatx2){acc[c][t][2], acc[c][t][3]});
        acc[c][t][0] = v0.x; acc[c][t][1] = v0.y; acc[c][t][2] = v1.x; acc[c][t][3] = v1.y;
      }
      floatx2 q01 = (floatx2){0.f, 0.f}, q23 = (floatx2){0.f, 0.f};
#pragma unroll
      for (int t = 0; t < 8; ++t) {
        const floatx2 wv = (floatx2){winfv[t], winfv[t]};
        q01 += (floatx2){acc[c][t][0], acc[c][t][1]} * wv;
        q23 += (floatx2){acc[c][t][2], acc[c][t][3]} * wv;
      }
      float pp[4] = {q01.x, q01.y, q23.x, q23.y};
#pragma unroll
      for (int off = 1; off <= 8; off <<= 1)
#pragma unroll
        for (int r = 0; r < 4; ++r) pp[r] += __shfl_xor(pp[r], off);
      float e[4];
#pragma unroll
      for (int r = 0; r < 4; ++r) {
        const int jg = ch * 128 + c * 64 + w * 16 + lg * 4 + r;
        float x = pp[r] + binf;
        e[r] = __builtin_amdgcn_rcpf(1.f + __expf(-x));
        if (jg == i) e[r] = 0.f;
      }
      const floatx2 e01 = (floatx2){e[0], e[1]}, e23 = (floatx2){e[2], e[3]};
#pragma unroll
      for (int t = 0; t < 8; ++t) {
        mpp[t] += (floatx2){acc[c][t][0], acc[c][t][1]} * e01;
        mpp[t] += (floatx2){acc[c][t][2], acc[c][t][3]} * e23;
      }
    }
    float mp[8];
#pragma unroll
    for (int t = 0; t < 8; ++t) {
      mp[t] = mpp[t].x + mpp[t].y;
      mp[t] += __shfl_xor(mp[t], 16);
      mp[t] += __shfl_xor(mp[t], 32);
    }
    if (lg == 0) {
#pragma unroll
      for (int t = 0; t < 8; ++t) sMp[w * 128 + t * 16 + l16] = mp[t];
    }
    __syncthreads();
    if (tid < 128) {
      float v = sMp[tid] + sMp[128 + tid] + sMp[256 + tid] + sMp[384 + tid];
      (ch ? p.mp1 : p.mp0)[(size_t)(b * 256 + i) * 128 + tid] = v;
    }
  }
}

// ---------------- P3/P5: node MLP (+ optional next-iter proj), grid-stride 128 units ----------------
__device__ void phase_node(const Prm& p, char* smem, const float* h_in, float* h_out, int do_proj) {
  ushort_t (*sA)[264]  = (ushort_t(*)[264])smem;
  ushort_t (*sU)[136]  = (ushort_t(*)[136])(smem + 8448);
  ushort_t (*sHp)[136] = (ushort_t(*)[136])(smem + 12800);
  const int tid = threadIdx.x;
  const int w = tid >> 6, lane = tid & 63, l16 = lane & 15, lg = lane >> 4;
  for (int blk = blockIdx.x; blk < 128; blk += gridDim.x) {
    const int m0 = blk * 16;
    {
      const int row = tid >> 4, c0 = (tid & 15) * 16;
      unsigned int* dst = (unsigned int*)&sA[row][c0];
      if (c0 < 128) {
        const float* src = h_in + (size_t)(m0 + row) * 128 + c0;
#pragma unroll
        for (int x = 0; x < 8; ++x) dst[x] = pk2bf(src[2 * x], src[2 * x + 1]);
      } else {
        const float* s0 = p.mp0 + (size_t)(m0 + row) * 128 + (c0 - 128);
        const float* s1 = p.mp1 + (size_t)(m0 + row) * 128 + (c0 - 128);
#pragma unroll
        for (int x = 0; x < 8; ++x)
          dst[x] = pk2bf(s0[2 * x] + s1[2 * x], s0[2 * x + 1] + s1[2 * x + 1]);
      }
    }
    __syncthreads();
    floatx4 au[2];
#pragma unroll
    for (int q = 0; q < 2; ++q) { float bv = p.b_h1[(2 * w + q) * 16 + l16]; au[q] = (floatx4){bv, bv, bv, bv}; }
    const shortx8* W1 = (const shortx8*)p.wh1f;
#pragma unroll
    for (int s = 0; s < 8; ++s) {
      shortx8 af = *(const shortx8*)&sA[l16][s * 32 + lg * 8];
#pragma unroll
      for (int q = 0; q < 2; ++q)
        au[q] = __builtin_amdgcn_mfma_f32_16x16x32_bf16(af, W1[(s * 8 + 2 * w + q) * 64 + lane], au[q], 0, 0, 0);
    }
#pragma unroll
    for (int q = 0; q < 2; ++q)
#pragma unroll
      for (int r = 0; r < 4; ++r)
        sU[lg * 4 + r][(2 * w + q) * 16 + l16] = f2bf_rhu(lk(au[q][r]));
    __syncthreads();
    floatx4 ah[2];
#pragma unroll
    for (int q = 0; q < 2; ++q) { float bv = p.b_h2[(2 * w + q) * 16 + l16]; ah[q] = (floatx4){bv, bv, bv, bv}; }
    const shortx8* W2 = (const shortx8*)p.wh2f;
#pragma unroll
    for (int s = 0; s < 4; ++s) {
      shortx8 af = *(const shortx8*)&sU[l16][s * 32 + lg * 8];
#pragma unroll
      for (int q = 0; q < 2; ++q)
        ah[q] = __builtin_amdgcn_mfma_f32_16x16x32_bf16(af, W2[(s * 8 + 2 * w + q) * 64 + lane], ah[q], 0, 0, 0);
    }
#pragma unroll
    for (int q = 0; q < 2; ++q) {
      const int n = (2 * w + q) * 16 + l16;
#pragma unroll
      for (int r = 0; r < 4; ++r) {
        const int m = m0 + lg * 4 + r;
        float v = ah[q][r] + h_in[(size_t)m * 128 + n];
        h_out[(size_t)m * 128 + n] = v;
        sHp[lg * 4 + r][n] = f2bf_rhu(v);
      }
    }
    if (do_proj) {
      __syncthreads();
      floatx4 ap[4];
#pragma unroll
      for (int q = 0; q < 4; ++q) ap[q] = (floatx4){0.f, 0.f, 0.f, 0.f};
      const shortx8* Wp = (const shortx8*)p.wijf;
#pragma unroll
      for (int s = 0; s < 4; ++s) {
        shortx8 af = *(const shortx8*)&sHp[l16][s * 32 + lg * 8];
#pragma unroll
        for (int q = 0; q < 4; ++q)
          ap[q] = __builtin_amdgcn_mfma_f32_16x16x32_bf16(af, Wp[(s * 16 + 4 * w + q) * 64 + lane], ap[q], 0, 0, 0);
      }
#pragma unroll
      for (int q = 0; q < 4; ++q) {
        const int n = (4 * w + q) * 16 + l16;
#pragma unroll
        for (int r = 0; r < 4; ++r) proj_store(p, ap[q][r], m0 + lg * 4 + r, n);
      }
    }
    __syncthreads();
  }
}

// ---------------- single cooperative kernel ----------------
__global__ __launch_bounds__(256, 4) void fused(Prm p) {
  __shared__ __align__(16) char smem[36864];
  cg::grid_group g = cg::this_grid();
  phase_prep(p);
  g.sync();
  phase_h0proj(p, smem);
  g.sync();
  phase_edge(p, smem);
  g.sync();
  phase_node(p, smem, p.hA, p.hB, 1);
  g.sync();
  phase_edge(p, smem);
  g.sync();
  phase_node(p, smem, p.hB, p.out, 0);
}

// ---------------- fallback wrappers (same phase code, no grid sync) ----------------
__global__ __launch_bounds__(256, 4) void k_prep(Prm p) { phase_prep(p); }
__global__ __launch_bounds__(256, 4) void k_h0(Prm p) {
  __shared__ __align__(16) char smem[4352]; phase_h0proj(p, smem);
}
__global__ __launch_bounds__(256, 4) void k_edge(Prm p) {
  __shared__ __align__(16) char smem[36864]; phase_edge(p, smem);
}
__global__ __launch_bounds__(256, 4) void k_node(Prm p, const float* hi, float* ho, int dp) {
  __shared__ __align__(16) char smem[17152]; phase_node(p, smem, hi, ho, dp);
}

extern "C" void kernel_launch(void* const* d_in, const int* in_sizes, int n_in,
                              void* d_out, int out_size, void* d_ws, size_t ws_size,
                              hipStream_t stream) {
  char* ws = (char*)d_ws;
  Prm p;
  p.fres   = (const float*)d_in[0];
  p.coords = (const float*)d_in[1];
  p.W_emb  = (const float*)d_in[2];
  p.W_e1   = (const float*)d_in[3];
  p.b_e1   = (const float*)d_in[4];
  p.W_e2   = (const float*)d_in[5];
  p.b_e2   = (const float*)d_in[6];
  p.W_inf  = (const float*)d_in[7];
  p.b_inf  = (const float*)d_in[8];
  p.W_h1   = (const float*)d_in[9];
  p.b_h1   = (const float*)d_in[10];
  p.W_h2   = (const float*)d_in[11];
  p.b_h2   = (const float*)d_in[12];
  p.out    = (float*)d_out;
  p.hA   = (float*)(ws + (0 << 20));
  p.hB   = (float*)(ws + (1 << 20));
  p.tib  = (float*)(ws + (2 << 20));
  p.tjf  = (float*)(ws + (3 << 20));
  p.mp0  = (float*)(ws + (4 << 20));
  p.mp1  = (float*)(ws + (5 << 20));
  p.wijf = (ushort_t*)(ws + (6 << 20));
  p.we2f = p.wijf + 32768;
  p.wh1f = p.we2f + 16384;
  p.wh2f = p.wh1f + 32768;

  // derive a co-residency-safe grid every call (deterministic; capture-safe host query)
  int nb = 0;
  hipError_t qerr = hipOccupancyMaxActiveBlocksPerMultiprocessor(&nb, (const void*)fused, 256, 0);
  bool coop = (qerr == hipSuccess) && (nb >= 1);
  if (coop) {
    int grid = nb * 256;
    if (grid > 1024) grid = 1024;
    void* args[] = { &p };
    hipError_t lerr = hipLaunchCooperativeKernel((const void*)fused, dim3(grid), dim3(256),
                                                 args, 0, stream);
    if (lerr != hipSuccess) coop = false;
  }
  if (!coop) {
    k_prep<<<384, 256, 0, stream>>>(p);
    k_h0<<<128, 256, 0, stream>>>(p);
    k_edge<<<1024, 256, 0, stream>>>(p);
    k_node<<<128, 256, 0, stream>>>(p, p.hA, p.hB, 1);
    k_edge<<<1024, 256, 0, stream>>>(p);
    k_node<<<128, 256, 0, stream>>>(p, p.hB, p.out, 0);
  }
}

// Round 7
// 235.386 us; speedup vs baseline: 2.0591x; 2.0591x over previous
//
#include <hip/hip_runtime.h>

typedef unsigned short ushort_t;
typedef __attribute__((ext_vector_type(8))) short shortx8;
typedef __attribute__((ext_vector_type(4))) float floatx4;
typedef __attribute__((ext_vector_type(2))) float floatx2;

#define NS 0.1f

__device__ __forceinline__ ushort_t f2bf_rne(float f) {
  union { float f; unsigned int u; } v; v.f = f;
  unsigned int r = v.u + 0x7FFFu + ((v.u >> 16) & 1u);
  return (ushort_t)(r >> 16);
}
// pack two f32 -> bf16x2 (round-half-up): low16=bf(a), high16=bf(b)
__device__ __forceinline__ unsigned int pk2bf(float a, float b) {
  union { float f; unsigned int u; } x, y; x.f = a; y.f = b;
  return __builtin_amdgcn_perm(y.u + 0x8000u, x.u + 0x8000u, 0x07060302u);
}
__device__ __forceinline__ ushort_t f2bf_rhu(float f) {
  union { float f; unsigned int u; } v; v.f = f;
  return (ushort_t)((v.u + 0x8000u) >> 16);
}
__device__ __forceinline__ float lk(float x) { return fmaxf(x, NS * x); }
__device__ __forceinline__ floatx2 lk2(floatx2 v) {
  return __builtin_elementwise_max(v, v * (floatx2){NS, NS});
}

// ---------------- prep: weights -> fragment-linear bf16 ----------------
// element e = f*8+j, f = (s*NT + t)*64 + lane,
// value = W[k = s*32 + (lane>>4)*8 + j][n = t*16 + (lane&15)]  (W is KxN row-major)
__global__ __launch_bounds__(256) void prep_w(
    const float* __restrict__ W_e1, const float* __restrict__ W_e2,
    const float* __restrict__ W_h1, const float* __restrict__ W_h2,
    ushort_t* __restrict__ wijf, ushort_t* __restrict__ we2f,
    ushort_t* __restrict__ wh1f, ushort_t* __restrict__ wh2f) {
  int e = blockIdx.x * 256 + threadIdx.x;
  if (e >= 98304) return;
  int which, le;
  if (e < 32768) { which = 0; le = e; }
  else if (e < 49152) { which = 1; le = e - 32768; }
  else if (e < 81920) { which = 2; le = e - 49152; }
  else { which = 3; le = e - 81920; }
  const int NT = (which == 0) ? 16 : 8;
  int f = le >> 3, j = le & 7;
  int lane = f & 63, ft = f >> 6;
  int t = ft % NT, s = ft / NT;
  int n = t * 16 + (lane & 15), k = s * 32 + (lane >> 4) * 8 + j;
  float v; ushort_t* d;
  if (which == 0) { v = (n < 128) ? W_e1[k * 128 + n] : W_e1[(128 + k) * 128 + (n - 128)]; d = wijf; }
  else if (which == 1) { v = W_e2[k * 128 + n]; d = we2f; }
  else if (which == 2) { v = W_h1[k * 128 + n]; d = wh1f; }
  else { v = W_h2[k * 128 + n]; d = wh2f; }
  d[le] = f2bf_rne(v);
}

// proj epilogue store: ti plain [m][n<128]; tj fragment-linear for edge kernel
__device__ __forceinline__ void proj_store(float v, int m, int n,
                                           float* __restrict__ tib, float* __restrict__ tjf) {
  if (n < 128) {
    tib[(size_t)m * 128 + n] = v;
  } else {
    int k = n - 128, b = m >> 8, j = m & 255;
    int s = k >> 5, lg2 = (k >> 3) & 3, j8 = k & 7;
    tjf[((((size_t)(b * 4 + s)) * 256 + j) * 4 + lg2) * 8 + j8] = v;
  }
}

// ---------------- h0 = leaky(fres @ W_emb) fused with proj ----------------
__global__ __launch_bounds__(256) void h0_proj(
    const float* __restrict__ fres, const float* __restrict__ Wemb,
    const ushort_t* __restrict__ wijf, float* __restrict__ h_out,
    float* __restrict__ tib, float* __restrict__ tjf) {
  const int m0 = blockIdx.x * 16;
  const int tid = threadIdx.x;
  const int w = tid >> 6, lane = tid & 63, l16 = lane & 15, lg = lane >> 4;
  __shared__ __align__(16) ushort_t sH[16][136];
  {
    const int row = tid >> 4, c0 = (tid & 15) * 8;
    const float* fr = fres + (size_t)(m0 + row) * 20;
    float a[8] = {0, 0, 0, 0, 0, 0, 0, 0};
    for (int k = 0; k < 20; ++k) {
      float fv = fr[k];
      float4 w0 = *(const float4*)(Wemb + k * 128 + c0);
      float4 w1 = *(const float4*)(Wemb + k * 128 + c0 + 4);
      a[0] += fv * w0.x; a[1] += fv * w0.y; a[2] += fv * w0.z; a[3] += fv * w0.w;
      a[4] += fv * w1.x; a[5] += fv * w1.y; a[6] += fv * w1.z; a[7] += fv * w1.w;
    }
#pragma unroll
    for (int x = 0; x < 8; ++x) a[x] = lk(a[x]);
    float* ho = h_out + (size_t)(m0 + row) * 128 + c0;
    *(float4*)ho = (float4){a[0], a[1], a[2], a[3]};
    *(float4*)(ho + 4) = (float4){a[4], a[5], a[6], a[7]};
    unsigned int* sh = (unsigned int*)&sH[row][c0];
    sh[0] = pk2bf(a[0], a[1]); sh[1] = pk2bf(a[2], a[3]);
    sh[2] = pk2bf(a[4], a[5]); sh[3] = pk2bf(a[6], a[7]);
  }
  __syncthreads();
  floatx4 ap[4];
#pragma unroll
  for (int q = 0; q < 4; ++q) ap[q] = (floatx4){0.f, 0.f, 0.f, 0.f};
  const shortx8* Wp = (const shortx8*)wijf;
#pragma unroll
  for (int s = 0; s < 4; ++s) {
    shortx8 af = *(const shortx8*)&sH[l16][s * 32 + lg * 8];
#pragma unroll
    for (int q = 0; q < 4; ++q)
      ap[q] = __builtin_amdgcn_mfma_f32_16x16x32_bf16(af, Wp[(s * 16 + 4 * w + q) * 64 + lane], ap[q], 0, 0, 0);
  }
#pragma unroll
  for (int q = 0; q < 4; ++q) {
    const int n = (4 * w + q) * 16 + l16;
#pragma unroll
    for (int r = 0; r < 4; ++r) proj_store(ap[q][r], m0 + lg * 4 + r, n, tib, tjf);
  }
}

// ---------------- edge kernel v5: one block per (b,i), ch-paired, staged once ----------------
__global__ __launch_bounds__(256, 4) void edge_kernel(
    const float* __restrict__ tib, const float* __restrict__ tjf,
    const float* __restrict__ coords, const ushort_t* __restrict__ we2f,
    const float* __restrict__ W_e1, const float* __restrict__ b_e1,
    const float* __restrict__ b_e2, const float* __restrict__ W_inf,
    const float* __restrict__ b_inf, float* __restrict__ mp0, float* __restrict__ mp1) {
  const int blk = blockIdx.x;           // b*256 + i
  const int b = blk >> 8, i = blk & 255;
  const int tid = threadIdx.x;
  const int w = tid >> 6, lane = tid & 63, l16 = lane & 15, lg = lane >> 4;

  __shared__ __align__(16) ushort_t sW[16384];   // 32 KB We2 fragment-linear
  __shared__ __align__(16) float sTiP[128];
  __shared__ __align__(16) float sWd[128];
  __shared__ __align__(16) float sD2[256];
  __shared__ __align__(16) float sMp[4][128];

  {
    shortx8* dst = (shortx8*)sW;
    const shortx8* src = (const shortx8*)we2f;
#pragma unroll
    for (int r = 0; r < 8; ++r) dst[r * 256 + tid] = src[r * 256 + tid];
  }
  if (tid < 128) {
    sTiP[tid] = tib[(size_t)blk * 128 + tid] + b_e1[tid];
    sWd[tid] = W_e1[256 * 128 + tid];
  }
  {
    const int j = tid;
    float dx = coords[(size_t)(b * 256 + i) * 3 + 0] - coords[(size_t)(b * 256 + j) * 3 + 0];
    float dy = coords[(size_t)(b * 256 + i) * 3 + 1] - coords[(size_t)(b * 256 + j) * 3 + 1];
    float dz = coords[(size_t)(b * 256 + i) * 3 + 2] - coords[(size_t)(b * 256 + j) * 3 + 2];
    sD2[j] = dx * dx + dy * dy + dz * dz;
  }
  float bev[8], winfv[8];
#pragma unroll
  for (int t = 0; t < 8; ++t) {
    bev[t] = b_e2[t * 16 + l16];
    winfv[t] = W_inf[t * 16 + l16];
  }
  const float binf = b_inf[0];
  __syncthreads();

  const shortx8* sWf = (const shortx8*)sW;

  for (int ch = 0; ch < 2; ++ch) {
    float d2a0 = sD2[ch * 128 + w * 16 + l16];
    float d2a1 = sD2[ch * 128 + 64 + w * 16 + l16];
    floatx4 acc[2][8];
#pragma unroll
    for (int t = 0; t < 8; ++t) {
      acc[0][t] = (floatx4){bev[t], bev[t], bev[t], bev[t]};
      acc[1][t] = acc[0][t];
    }
#pragma unroll
    for (int s = 0; s < 4; ++s) {
      const int k0 = s * 32 + lg * 8;
      floatx2 p2[4], w2[4];
#pragma unroll
      for (int x = 0; x < 4; ++x) {
        p2[x] = *(const floatx2*)&sTiP[k0 + 2 * x];
        w2[x] = *(const floatx2*)&sWd[k0 + 2 * x];
      }
      shortx8 af[2];
#pragma unroll
      for (int c = 0; c < 2; ++c) {
        const int jr = ch * 128 + c * 64 + w * 16 + l16;
        const float* tb = tjf + (((size_t)(b * 4 + s) * 256 + jr) * 4 + lg) * 8;
        float4 t0 = *(const float4*)tb;
        float4 t1 = *(const float4*)(tb + 4);
        const float d2 = c ? d2a1 : d2a0;
        const floatx2 d2v = (floatx2){d2, d2};
        floatx2 pr0 = (floatx2){t0.x, t0.y} + (p2[0] + d2v * w2[0]);
        floatx2 pr1 = (floatx2){t0.z, t0.w} + (p2[1] + d2v * w2[1]);
        floatx2 pr2 = (floatx2){t1.x, t1.y} + (p2[2] + d2v * w2[2]);
        floatx2 pr3 = (floatx2){t1.z, t1.w} + (p2[3] + d2v * w2[3]);
        floatx2 l0 = lk2(pr0), l1 = lk2(pr1), l2 = lk2(pr2), l3 = lk2(pr3);
        union { shortx8 s8; unsigned int uu[4]; } A;
        A.uu[0] = pk2bf(l0.x, l0.y); A.uu[1] = pk2bf(l1.x, l1.y);
        A.uu[2] = pk2bf(l2.x, l2.y); A.uu[3] = pk2bf(l3.x, l3.y);
        af[c] = A.s8;
      }
#pragma unroll
      for (int tg = 0; tg < 2; ++tg) {
        shortx8 b0 = sWf[(s * 8 + tg * 4 + 0) * 64 + lane];
        shortx8 b1 = sWf[(s * 8 + tg * 4 + 1) * 64 + lane];
        shortx8 b2 = sWf[(s * 8 + tg * 4 + 2) * 64 + lane];
        shortx8 b3 = sWf[(s * 8 + tg * 4 + 3) * 64 + lane];
#pragma unroll
        for (int c = 0; c < 2; ++c) {
          acc[c][tg * 4 + 0] = __builtin_amdgcn_mfma_f32_16x16x32_bf16(af[c], b0, acc[c][tg * 4 + 0], 0, 0, 0);
          acc[c][tg * 4 + 1] = __builtin_amdgcn_mfma_f32_16x16x32_bf16(af[c], b1, acc[c][tg * 4 + 1], 0, 0, 0);
          acc[c][tg * 4 + 2] = __builtin_amdgcn_mfma_f32_16x16x32_bf16(af[c], b2, acc[c][tg * 4 + 2], 0, 0, 0);
          acc[c][tg * 4 + 3] = __builtin_amdgcn_mfma_f32_16x16x32_bf16(af[c], b3, acc[c][tg * 4 + 3], 0, 0, 0);
        }
      }
    }
    // packed epilogue: leaky, gate dot, masked weighted reduction
    floatx2 mpp[8];
#pragma unroll
    for (int t = 0; t < 8; ++t) mpp[t] = (floatx2){0.f, 0.f};
#pragma unroll
    for (int c = 0; c < 2; ++c) {
#pragma unroll
      for (int t = 0; t < 8; ++t) {
        floatx2 v0 = lk2((floatx2){acc[c][t][0], acc[c][t][1]});
        floatx2 v1 = lk2((floatx2){acc[c][t][2], acc[c][t][3]});
        acc[c][t][0] = v0.x; acc[c][t][1] = v0.y; acc[c][t][2] = v1.x; acc[c][t][3] = v1.y;
      }
      floatx2 q01 = (floatx2){0.f, 0.f}, q23 = (floatx2){0.f, 0.f};
#pragma unroll
      for (int t = 0; t < 8; ++t) {
        const floatx2 wv = (floatx2){winfv[t], winfv[t]};
        q01 += (floatx2){acc[c][t][0], acc[c][t][1]} * wv;
        q23 += (floatx2){acc[c][t][2], acc[c][t][3]} * wv;
      }
      float pp[4] = {q01.x, q01.y, q23.x, q23.y};
#pragma unroll
      for (int off = 1; off <= 8; off <<= 1)
#pragma unroll
        for (int r = 0; r < 4; ++r) pp[r] += __shfl_xor(pp[r], off);
      float e[4];
#pragma unroll
      for (int r = 0; r < 4; ++r) {
        const int jg = ch * 128 + c * 64 + w * 16 + lg * 4 + r;
        float x = pp[r] + binf;
        e[r] = __builtin_amdgcn_rcpf(1.f + __expf(-x));
        if (jg == i) e[r] = 0.f;
      }
      const floatx2 e01 = (floatx2){e[0], e[1]}, e23 = (floatx2){e[2], e[3]};
#pragma unroll
      for (int t = 0; t < 8; ++t) {
        mpp[t] += (floatx2){acc[c][t][0], acc[c][t][1]} * e01;
        mpp[t] += (floatx2){acc[c][t][2], acc[c][t][3]} * e23;
      }
    }
    float mp[8];
#pragma unroll
    for (int t = 0; t < 8; ++t) {
      mp[t] = mpp[t].x + mpp[t].y;
      mp[t] += __shfl_xor(mp[t], 16);
      mp[t] += __shfl_xor(mp[t], 32);
    }
    if (lg == 0) {
#pragma unroll
      for (int t = 0; t < 8; ++t) sMp[w][t * 16 + l16] = mp[t];
    }
    __syncthreads();
    if (tid < 128) {
      float v = sMp[0][tid] + sMp[1][tid] + sMp[2][tid] + sMp[3][tid];
      (ch ? mp1 : mp0)[(size_t)blk * 128 + tid] = v;
    }
    __syncthreads();   // sMp reuse fence for next ch
  }
}

// ---------------- fused node MLP (+ optional next-iter proj) ----------------
__global__ __launch_bounds__(256) void node_kernel(
    const float* __restrict__ h_in, const float* __restrict__ mp0, const float* __restrict__ mp1,
    const ushort_t* __restrict__ wh1f, const float* __restrict__ b_h1,
    const ushort_t* __restrict__ wh2f, const float* __restrict__ b_h2,
    const ushort_t* __restrict__ wijf, float* __restrict__ h_out,
    float* __restrict__ tib, float* __restrict__ tjf, const int do_proj) {
  const int m0 = blockIdx.x * 16;
  const int tid = threadIdx.x;
  const int w = tid >> 6, lane = tid & 63, l16 = lane & 15, lg = lane >> 4;
  __shared__ __align__(16) ushort_t sA[16][264];
  __shared__ __align__(16) ushort_t sU[16][136];
  __shared__ __align__(16) ushort_t sHp[16][136];
  {
    const int row = tid >> 4, c0 = (tid & 15) * 16;
    unsigned int* dst = (unsigned int*)&sA[row][c0];
    if (c0 < 128) {
      const float* src = h_in + (size_t)(m0 + row) * 128 + c0;
#pragma unroll
      for (int x = 0; x < 8; ++x) dst[x] = pk2bf(src[2 * x], src[2 * x + 1]);
    } else {
      const float* s0 = mp0 + (size_t)(m0 + row) * 128 + (c0 - 128);
      const float* s1 = mp1 + (size_t)(m0 + row) * 128 + (c0 - 128);
#pragma unroll
      for (int x = 0; x < 8; ++x)
        dst[x] = pk2bf(s0[2 * x] + s1[2 * x], s0[2 * x + 1] + s1[2 * x + 1]);
    }
  }
  __syncthreads();
  floatx4 au[2];
#pragma unroll
  for (int q = 0; q < 2; ++q) { float bv = b_h1[(2 * w + q) * 16 + l16]; au[q] = (floatx4){bv, bv, bv, bv}; }
  const shortx8* W1 = (const shortx8*)wh1f;
#pragma unroll
  for (int s = 0; s < 8; ++s) {
    shortx8 af = *(const shortx8*)&sA[l16][s * 32 + lg * 8];
#pragma unroll
    for (int q = 0; q < 2; ++q)
      au[q] = __builtin_amdgcn_mfma_f32_16x16x32_bf16(af, W1[(s * 8 + 2 * w + q) * 64 + lane], au[q], 0, 0, 0);
  }
#pragma unroll
  for (int q = 0; q < 2; ++q)
#pragma unroll
    for (int r = 0; r < 4; ++r)
      sU[lg * 4 + r][(2 * w + q) * 16 + l16] = f2bf_rhu(lk(au[q][r]));
  __syncthreads();
  floatx4 ah[2];
#pragma unroll
  for (int q = 0; q < 2; ++q) { float bv = b_h2[(2 * w + q) * 16 + l16]; ah[q] = (floatx4){bv, bv, bv, bv}; }
  const shortx8* W2 = (const shortx8*)wh2f;
#pragma unroll
  for (int s = 0; s < 4; ++s) {
    shortx8 af = *(const shortx8*)&sU[l16][s * 32 + lg * 8];
#pragma unroll
    for (int q = 0; q < 2; ++q)
      ah[q] = __builtin_amdgcn_mfma_f32_16x16x32_bf16(af, W2[(s * 8 + 2 * w + q) * 64 + lane], ah[q], 0, 0, 0);
  }
#pragma unroll
  for (int q = 0; q < 2; ++q) {
    const int n = (2 * w + q) * 16 + l16;
#pragma unroll
    for (int r = 0; r < 4; ++r) {
      const int m = m0 + lg * 4 + r;
      float v = ah[q][r] + h_in[(size_t)m * 128 + n];
      h_out[(size_t)m * 128 + n] = v;
      sHp[lg * 4 + r][n] = f2bf_rhu(v);
    }
  }
  if (!do_proj) return;
  __syncthreads();
  floatx4 ap[4];
#pragma unroll
  for (int q = 0; q < 4; ++q) ap[q] = (floatx4){0.f, 0.f, 0.f, 0.f};
  const shortx8* Wp = (const shortx8*)wijf;
#pragma unroll
  for (int s = 0; s < 4; ++s) {
    shortx8 af = *(const shortx8*)&sHp[l16][s * 32 + lg * 8];
#pragma unroll
    for (int q = 0; q < 4; ++q)
      ap[q] = __builtin_amdgcn_mfma_f32_16x16x32_bf16(af, Wp[(s * 16 + 4 * w + q) * 64 + lane], ap[q], 0, 0, 0);
  }
#pragma unroll
  for (int q = 0; q < 4; ++q) {
    const int n = (4 * w + q) * 16 + l16;
#pragma unroll
    for (int r = 0; r < 4; ++r) proj_store(ap[q][r], m0 + lg * 4 + r, n, tib, tjf);
  }
}

extern "C" void kernel_launch(void* const* d_in, const int* in_sizes, int n_in,
                              void* d_out, int out_size, void* d_ws, size_t ws_size,
                              hipStream_t stream) {
  const float* fres   = (const float*)d_in[0];
  const float* coords = (const float*)d_in[1];
  const float* W_emb  = (const float*)d_in[2];
  const float* W_e1   = (const float*)d_in[3];
  const float* b_e1   = (const float*)d_in[4];
  const float* W_e2   = (const float*)d_in[5];
  const float* b_e2   = (const float*)d_in[6];
  const float* W_inf  = (const float*)d_in[7];
  const float* b_inf  = (const float*)d_in[8];
  const float* W_h1   = (const float*)d_in[9];
  const float* b_h1   = (const float*)d_in[10];
  const float* W_h2   = (const float*)d_in[11];
  const float* b_h2   = (const float*)d_in[12];
  float* out = (float*)d_out;

  char* ws = (char*)d_ws;
  float* hA  = (float*)(ws + (0 << 20));
  float* hB  = (float*)(ws + (1 << 20));
  float* tib = (float*)(ws + (2 << 20));
  float* tjf = (float*)(ws + (3 << 20));
  float* mp0 = (float*)(ws + (4 << 20));
  float* mp1 = (float*)(ws + (5 << 20));
  ushort_t* wijf = (ushort_t*)(ws + (6 << 20));
  ushort_t* we2f = wijf + 32768;
  ushort_t* wh1f = we2f + 16384;
  ushort_t* wh2f = wh1f + 32768;

  prep_w<<<384, 256, 0, stream>>>(W_e1, W_e2, W_h1, W_h2, wijf, we2f, wh1f, wh2f);
  h0_proj<<<128, 256, 0, stream>>>(fres, W_emb, wijf, hA, tib, tjf);

  edge_kernel<<<2048, 256, 0, stream>>>(tib, tjf, coords, we2f, W_e1, b_e1, b_e2, W_inf, b_inf, mp0, mp1);
  node_kernel<<<128, 256, 0, stream>>>(hA, mp0, mp1, wh1f, b_h1, wh2f, b_h2, wijf, hB, tib, tjf, 1);

  edge_kernel<<<2048, 256, 0, stream>>>(tib, tjf, coords, we2f, W_e1, b_e1, b_e2, W_inf, b_inf, mp0, mp1);
  node_kernel<<<128, 256, 0, stream>>>(hB, mp0, mp1, wh1f, b_h1, wh2f, b_h2, wijf, out, tib, tjf, 0);
}

// Round 8
// 193.971 us; speedup vs baseline: 2.4987x; 1.2135x over previous
//
#include <hip/hip_runtime.h>

typedef unsigned short ushort_t;
typedef __attribute__((ext_vector_type(8))) short shortx8;
typedef __attribute__((ext_vector_type(4))) float floatx4;
typedef __attribute__((ext_vector_type(2))) float floatx2;

#define NS 0.1f

__device__ __forceinline__ ushort_t f2bf_rne(float f) {
  union { float f; unsigned int u; } v; v.f = f;
  unsigned int r = v.u + 0x7FFFu + ((v.u >> 16) & 1u);
  return (ushort_t)(r >> 16);
}
// pack two f32 -> bf16x2 (round-half-up): low16=bf(a), high16=bf(b)
__device__ __forceinline__ unsigned int pk2bf(float a, float b) {
  union { float f; unsigned int u; } x, y; x.f = a; y.f = b;
  return __builtin_amdgcn_perm(y.u + 0x8000u, x.u + 0x8000u, 0x07060302u);
}
__device__ __forceinline__ ushort_t f2bf_rhu(float f) {
  union { float f; unsigned int u; } v; v.f = f;
  return (ushort_t)((v.u + 0x8000u) >> 16);
}
__device__ __forceinline__ float lk(float x) { return fmaxf(x, NS * x); }
__device__ __forceinline__ floatx2 lk2(floatx2 v) {
  return __builtin_elementwise_max(v, v * (floatx2){NS, NS});
}

// ---------------- prep: weights -> fragment-linear bf16 ----------------
// element e = f*8+j, f = (s*NT + t)*64 + lane,
// value = W[k = s*32 + (lane>>4)*8 + j][n = t*16 + (lane&15)]  (W is KxN row-major)
__global__ __launch_bounds__(256) void prep_w(
    const float* __restrict__ W_e1, const float* __restrict__ W_e2,
    const float* __restrict__ W_h1, const float* __restrict__ W_h2,
    ushort_t* __restrict__ wijf, ushort_t* __restrict__ we2f,
    ushort_t* __restrict__ wh1f, ushort_t* __restrict__ wh2f) {
  int e = blockIdx.x * 256 + threadIdx.x;
  if (e >= 98304) return;
  int which, le;
  if (e < 32768) { which = 0; le = e; }
  else if (e < 49152) { which = 1; le = e - 32768; }
  else if (e < 81920) { which = 2; le = e - 49152; }
  else { which = 3; le = e - 81920; }
  const int NT = (which == 0) ? 16 : 8;
  int f = le >> 3, j = le & 7;
  int lane = f & 63, ft = f >> 6;
  int t = ft % NT, s = ft / NT;
  int n = t * 16 + (lane & 15), k = s * 32 + (lane >> 4) * 8 + j;
  float v; ushort_t* d;
  if (which == 0) { v = (n < 128) ? W_e1[k * 128 + n] : W_e1[(128 + k) * 128 + (n - 128)]; d = wijf; }
  else if (which == 1) { v = W_e2[k * 128 + n]; d = we2f; }
  else if (which == 2) { v = W_h1[k * 128 + n]; d = wh1f; }
  else { v = W_h2[k * 128 + n]; d = wh2f; }
  d[le] = f2bf_rne(v);
}

// proj epilogue store: ti plain [m][n<128]; tj fragment-linear for edge kernel
__device__ __forceinline__ void proj_store(float v, int m, int n,
                                           float* __restrict__ tib, float* __restrict__ tjf) {
  if (n < 128) {
    tib[(size_t)m * 128 + n] = v;
  } else {
    int k = n - 128, b = m >> 8, j = m & 255;
    int s = k >> 5, lg2 = (k >> 3) & 3, j8 = k & 7;
    tjf[((((size_t)(b * 4 + s)) * 256 + j) * 4 + lg2) * 8 + j8] = v;
  }
}

// ---------------- h0 = leaky(fres @ W_emb) fused with proj ----------------
__global__ __launch_bounds__(256) void h0_proj(
    const float* __restrict__ fres, const float* __restrict__ Wemb,
    const ushort_t* __restrict__ wijf, float* __restrict__ h_out,
    float* __restrict__ tib, float* __restrict__ tjf) {
  const int m0 = blockIdx.x * 16;
  const int tid = threadIdx.x;
  const int w = tid >> 6, lane = tid & 63, l16 = lane & 15, lg = lane >> 4;
  __shared__ __align__(16) ushort_t sH[16][136];
  {
    const int row = tid >> 4, c0 = (tid & 15) * 8;
    const float* fr = fres + (size_t)(m0 + row) * 20;
    float a[8] = {0, 0, 0, 0, 0, 0, 0, 0};
    for (int k = 0; k < 20; ++k) {
      float fv = fr[k];
      float4 w0 = *(const float4*)(Wemb + k * 128 + c0);
      float4 w1 = *(const float4*)(Wemb + k * 128 + c0 + 4);
      a[0] += fv * w0.x; a[1] += fv * w0.y; a[2] += fv * w0.z; a[3] += fv * w0.w;
      a[4] += fv * w1.x; a[5] += fv * w1.y; a[6] += fv * w1.z; a[7] += fv * w1.w;
    }
#pragma unroll
    for (int x = 0; x < 8; ++x) a[x] = lk(a[x]);
    float* ho = h_out + (size_t)(m0 + row) * 128 + c0;
    *(float4*)ho = (float4){a[0], a[1], a[2], a[3]};
    *(float4*)(ho + 4) = (float4){a[4], a[5], a[6], a[7]};
    unsigned int* sh = (unsigned int*)&sH[row][c0];
    sh[0] = pk2bf(a[0], a[1]); sh[1] = pk2bf(a[2], a[3]);
    sh[2] = pk2bf(a[4], a[5]); sh[3] = pk2bf(a[6], a[7]);
  }
  __syncthreads();
  floatx4 ap[4];
#pragma unroll
  for (int q = 0; q < 4; ++q) ap[q] = (floatx4){0.f, 0.f, 0.f, 0.f};
  const shortx8* Wp = (const shortx8*)wijf;
#pragma unroll
  for (int s = 0; s < 4; ++s) {
    shortx8 af = *(const shortx8*)&sH[l16][s * 32 + lg * 8];
#pragma unroll
    for (int q = 0; q < 4; ++q)
      ap[q] = __builtin_amdgcn_mfma_f32_16x16x32_bf16(af, Wp[(s * 16 + 4 * w + q) * 64 + lane], ap[q], 0, 0, 0);
  }
#pragma unroll
  for (int q = 0; q < 4; ++q) {
    const int n = (4 * w + q) * 16 + l16;
#pragma unroll
    for (int r = 0; r < 4; ++r) proj_store(ap[q][r], m0 + lg * 4 + r, n, tib, tjf);
  }
}

// ---------------- edge kernel v6: one block per (b,i), ch-paired, staged once, 3 waves/SIMD ----------------
__global__ __launch_bounds__(256, 3) void edge_kernel(
    const float* __restrict__ tib, const float* __restrict__ tjf,
    const float* __restrict__ coords, const ushort_t* __restrict__ we2f,
    const float* __restrict__ W_e1, const float* __restrict__ b_e1,
    const float* __restrict__ b_e2, const float* __restrict__ W_inf,
    const float* __restrict__ b_inf, float* __restrict__ mp0, float* __restrict__ mp1) {
  const int blk = blockIdx.x;           // b*256 + i
  const int b = blk >> 8, i = blk & 255;
  const int tid = threadIdx.x;
  const int w = tid >> 6, lane = tid & 63, l16 = lane & 15, lg = lane >> 4;

  __shared__ __align__(16) ushort_t sW[16384];   // 32 KB We2 fragment-linear
  __shared__ __align__(16) float sTiP[128];
  __shared__ __align__(16) float sWd[128];
  __shared__ __align__(16) float sD2[256];
  __shared__ __align__(16) float sMp[4][128];

  {
    shortx8* dst = (shortx8*)sW;
    const shortx8* src = (const shortx8*)we2f;
#pragma unroll
    for (int r = 0; r < 8; ++r) dst[r * 256 + tid] = src[r * 256 + tid];
  }
  if (tid < 128) {
    sTiP[tid] = tib[(size_t)blk * 128 + tid] + b_e1[tid];
    sWd[tid] = W_e1[256 * 128 + tid];
  }
  {
    const int j = tid;
    float dx = coords[(size_t)(b * 256 + i) * 3 + 0] - coords[(size_t)(b * 256 + j) * 3 + 0];
    float dy = coords[(size_t)(b * 256 + i) * 3 + 1] - coords[(size_t)(b * 256 + j) * 3 + 1];
    float dz = coords[(size_t)(b * 256 + i) * 3 + 2] - coords[(size_t)(b * 256 + j) * 3 + 2];
    sD2[j] = dx * dx + dy * dy + dz * dz;
  }
  float bev[8], winfv[8];
#pragma unroll
  for (int t = 0; t < 8; ++t) {
    bev[t] = b_e2[t * 16 + l16];
    winfv[t] = W_inf[t * 16 + l16];
  }
  const float binf = b_inf[0];
  __syncthreads();

  const shortx8* sWf = (const shortx8*)sW;

  for (int ch = 0; ch < 2; ++ch) {
    float d2a0 = sD2[ch * 128 + w * 16 + l16];
    float d2a1 = sD2[ch * 128 + 64 + w * 16 + l16];
    floatx4 acc[2][8];
#pragma unroll
    for (int t = 0; t < 8; ++t) {
      acc[0][t] = (floatx4){bev[t], bev[t], bev[t], bev[t]};
      acc[1][t] = acc[0][t];
    }
#pragma unroll
    for (int s = 0; s < 4; ++s) {
      const int k0 = s * 32 + lg * 8;
      floatx2 p2[4], w2[4];
#pragma unroll
      for (int x = 0; x < 4; ++x) {
        p2[x] = *(const floatx2*)&sTiP[k0 + 2 * x];
        w2[x] = *(const floatx2*)&sWd[k0 + 2 * x];
      }
      shortx8 af[2];
#pragma unroll
      for (int c = 0; c < 2; ++c) {
        const int jr = ch * 128 + c * 64 + w * 16 + l16;
        const float* tb = tjf + (((size_t)(b * 4 + s) * 256 + jr) * 4 + lg) * 8;
        float4 t0 = *(const float4*)tb;
        float4 t1 = *(const float4*)(tb + 4);
        const float d2 = c ? d2a1 : d2a0;
        const floatx2 d2v = (floatx2){d2, d2};
        floatx2 pr0 = (floatx2){t0.x, t0.y} + (p2[0] + d2v * w2[0]);
        floatx2 pr1 = (floatx2){t0.z, t0.w} + (p2[1] + d2v * w2[1]);
        floatx2 pr2 = (floatx2){t1.x, t1.y} + (p2[2] + d2v * w2[2]);
        floatx2 pr3 = (floatx2){t1.z, t1.w} + (p2[3] + d2v * w2[3]);
        floatx2 l0 = lk2(pr0), l1 = lk2(pr1), l2 = lk2(pr2), l3 = lk2(pr3);
        union { shortx8 s8; unsigned int uu[4]; } A;
        A.uu[0] = pk2bf(l0.x, l0.y); A.uu[1] = pk2bf(l1.x, l1.y);
        A.uu[2] = pk2bf(l2.x, l2.y); A.uu[3] = pk2bf(l3.x, l3.y);
        af[c] = A.s8;
      }
#pragma unroll
      for (int tg = 0; tg < 2; ++tg) {
        shortx8 b0 = sWf[(s * 8 + tg * 4 + 0) * 64 + lane];
        shortx8 b1 = sWf[(s * 8 + tg * 4 + 1) * 64 + lane];
        shortx8 b2 = sWf[(s * 8 + tg * 4 + 2) * 64 + lane];
        shortx8 b3 = sWf[(s * 8 + tg * 4 + 3) * 64 + lane];
#pragma unroll
        for (int c = 0; c < 2; ++c) {
          acc[c][tg * 4 + 0] = __builtin_amdgcn_mfma_f32_16x16x32_bf16(af[c], b0, acc[c][tg * 4 + 0], 0, 0, 0);
          acc[c][tg * 4 + 1] = __builtin_amdgcn_mfma_f32_16x16x32_bf16(af[c], b1, acc[c][tg * 4 + 1], 0, 0, 0);
          acc[c][tg * 4 + 2] = __builtin_amdgcn_mfma_f32_16x16x32_bf16(af[c], b2, acc[c][tg * 4 + 2], 0, 0, 0);
          acc[c][tg * 4 + 3] = __builtin_amdgcn_mfma_f32_16x16x32_bf16(af[c], b3, acc[c][tg * 4 + 3], 0, 0, 0);
        }
      }
    }
    // packed epilogue: leaky, gate dot, masked weighted reduction
    floatx2 mpp[8];
#pragma unroll
    for (int t = 0; t < 8; ++t) mpp[t] = (floatx2){0.f, 0.f};
#pragma unroll
    for (int c = 0; c < 2; ++c) {
#pragma unroll
      for (int t = 0; t < 8; ++t) {
        floatx2 v0 = lk2((floatx2){acc[c][t][0], acc[c][t][1]});
        floatx2 v1 = lk2((floatx2){acc[c][t][2], acc[c][t][3]});
        acc[c][t][0] = v0.x; acc[c][t][1] = v0.y; acc[c][t][2] = v1.x; acc[c][t][3] = v1.y;
      }
      floatx2 q01 = (floatx2){0.f, 0.f}, q23 = (floatx2){0.f, 0.f};
#pragma unroll
      for (int t = 0; t < 8; ++t) {
        const floatx2 wv = (floatx2){winfv[t], winfv[t]};
        q01 += (floatx2){acc[c][t][0], acc[c][t][1]} * wv;
        q23 += (floatx2){acc[c][t][2], acc[c][t][3]} * wv;
      }
      float pp[4] = {q01.x, q01.y, q23.x, q23.y};
#pragma unroll
      for (int off = 1; off <= 8; off <<= 1)
#pragma unroll
        for (int r = 0; r < 4; ++r) pp[r] += __shfl_xor(pp[r], off);
      float e[4];
#pragma unroll
      for (int r = 0; r < 4; ++r) {
        const int jg = ch * 128 + c * 64 + w * 16 + lg * 4 + r;
        float x = pp[r] + binf;
        e[r] = __builtin_amdgcn_rcpf(1.f + __expf(-x));
        if (jg == i) e[r] = 0.f;
      }
      const floatx2 e01 = (floatx2){e[0], e[1]}, e23 = (floatx2){e[2], e[3]};
#pragma unroll
      for (int t = 0; t < 8; ++t) {
        mpp[t] += (floatx2){acc[c][t][0], acc[c][t][1]} * e01;
        mpp[t] += (floatx2){acc[c][t][2], acc[c][t][3]} * e23;
      }
    }
    float mp[8];
#pragma unroll
    for (int t = 0; t < 8; ++t) {
      mp[t] = mpp[t].x + mpp[t].y;
      mp[t] += __shfl_xor(mp[t], 16);
      mp[t] += __shfl_xor(mp[t], 32);
    }
    if (lg == 0) {
#pragma unroll
      for (int t = 0; t < 8; ++t) sMp[w][t * 16 + l16] = mp[t];
    }
    __syncthreads();
    if (tid < 128) {
      float v = sMp[0][tid] + sMp[1][tid] + sMp[2][tid] + sMp[3][tid];
      (ch ? mp1 : mp0)[(size_t)blk * 128 + tid] = v;
    }
    __syncthreads();   // sMp reuse fence for next ch
  }
}

// ---------------- fused node MLP (+ optional next-iter proj) ----------------
__global__ __launch_bounds__(256) void node_kernel(
    const float* __restrict__ h_in, const float* __restrict__ mp0, const float* __restrict__ mp1,
    const ushort_t* __restrict__ wh1f, const float* __restrict__ b_h1,
    const ushort_t* __restrict__ wh2f, const float* __restrict__ b_h2,
    const ushort_t* __restrict__ wijf, float* __restrict__ h_out,
    float* __restrict__ tib, float* __restrict__ tjf, const int do_proj) {
  const int m0 = blockIdx.x * 16;
  const int tid = threadIdx.x;
  const int w = tid >> 6, lane = tid & 63, l16 = lane & 15, lg = lane >> 4;
  __shared__ __align__(16) ushort_t sA[16][264];
  __shared__ __align__(16) ushort_t sU[16][136];
  __shared__ __align__(16) ushort_t sHp[16][136];
  {
    const int row = tid >> 4, c0 = (tid & 15) * 16;
    unsigned int* dst = (unsigned int*)&sA[row][c0];
    if (c0 < 128) {
      const float* src = h_in + (size_t)(m0 + row) * 128 + c0;
#pragma unroll
      for (int x = 0; x < 8; ++x) dst[x] = pk2bf(src[2 * x], src[2 * x + 1]);
    } else {
      const float* s0 = mp0 + (size_t)(m0 + row) * 128 + (c0 - 128);
      const float* s1 = mp1 + (size_t)(m0 + row) * 128 + (c0 - 128);
#pragma unroll
      for (int x = 0; x < 8; ++x)
        dst[x] = pk2bf(s0[2 * x] + s1[2 * x], s0[2 * x + 1] + s1[2 * x + 1]);
    }
  }
  __syncthreads();
  floatx4 au[2];
#pragma unroll
  for (int q = 0; q < 2; ++q) { float bv = b_h1[(2 * w + q) * 16 + l16]; au[q] = (floatx4){bv, bv, bv, bv}; }
  const shortx8* W1 = (const shortx8*)wh1f;
#pragma unroll
  for (int s = 0; s < 8; ++s) {
    shortx8 af = *(const shortx8*)&sA[l16][s * 32 + lg * 8];
#pragma unroll
    for (int q = 0; q < 2; ++q)
      au[q] = __builtin_amdgcn_mfma_f32_16x16x32_bf16(af, W1[(s * 8 + 2 * w + q) * 64 + lane], au[q], 0, 0, 0);
  }
#pragma unroll
  for (int q = 0; q < 2; ++q)
#pragma unroll
    for (int r = 0; r < 4; ++r)
      sU[lg * 4 + r][(2 * w + q) * 16 + l16] = f2bf_rhu(lk(au[q][r]));
  __syncthreads();
  floatx4 ah[2];
#pragma unroll
  for (int q = 0; q < 2; ++q) { float bv = b_h2[(2 * w + q) * 16 + l16]; ah[q] = (floatx4){bv, bv, bv, bv}; }
  const shortx8* W2 = (const shortx8*)wh2f;
#pragma unroll
  for (int s = 0; s < 4; ++s) {
    shortx8 af = *(const shortx8*)&sU[l16][s * 32 + lg * 8];
#pragma unroll
    for (int q = 0; q < 2; ++q)
      ah[q] = __builtin_amdgcn_mfma_f32_16x16x32_bf16(af, W2[(s * 8 + 2 * w + q) * 64 + lane], ah[q], 0, 0, 0);
  }
#pragma unroll
  for (int q = 0; q < 2; ++q) {
    const int n = (2 * w + q) * 16 + l16;
#pragma unroll
    for (int r = 0; r < 4; ++r) {
      const int m = m0 + lg * 4 + r;
      float v = ah[q][r] + h_in[(size_t)m * 128 + n];
      h_out[(size_t)m * 128 + n] = v;
      sHp[lg * 4 + r][n] = f2bf_rhu(v);
    }
  }
  if (!do_proj) return;
  __syncthreads();
  floatx4 ap[4];
#pragma unroll
  for (int q = 0; q < 4; ++q) ap[q] = (floatx4){0.f, 0.f, 0.f, 0.f};
  const shortx8* Wp = (const shortx8*)wijf;
#pragma unroll
  for (int s = 0; s < 4; ++s) {
    shortx8 af = *(const shortx8*)&sHp[l16][s * 32 + lg * 8];
#pragma unroll
    for (int q = 0; q < 4; ++q)
      ap[q] = __builtin_amdgcn_mfma_f32_16x16x32_bf16(af, Wp[(s * 16 + 4 * w + q) * 64 + lane], ap[q], 0, 0, 0);
  }
#pragma unroll
  for (int q = 0; q < 4; ++q) {
    const int n = (4 * w + q) * 16 + l16;
#pragma unroll
    for (int r = 0; r < 4; ++r) proj_store(ap[q][r], m0 + lg * 4 + r, n, tib, tjf);
  }
}

extern "C" void kernel_launch(void* const* d_in, const int* in_sizes, int n_in,
                              void* d_out, int out_size, void* d_ws, size_t ws_size,
                              hipStream_t stream) {
  const float* fres   = (const float*)d_in[0];
  const float* coords = (const float*)d_in[1];
  const float* W_emb  = (const float*)d_in[2];
  const float* W_e1   = (const float*)d_in[3];
  const float* b_e1   = (const float*)d_in[4];
  const float* W_e2   = (const float*)d_in[5];
  const float* b_e2   = (const float*)d_in[6];
  const float* W_inf  = (const float*)d_in[7];
  const float* b_inf  = (const float*)d_in[8];
  const float* W_h1   = (const float*)d_in[9];
  const float* b_h1   = (const float*)d_in[10];
  const float* W_h2   = (const float*)d_in[11];
  const float* b_h2   = (const float*)d_in[12];
  float* out = (float*)d_out;

  char* ws = (char*)d_ws;
  float* hA  = (float*)(ws + (0 << 20));
  float* hB  = (float*)(ws + (1 << 20));
  float* tib = (float*)(ws + (2 << 20));
  float* tjf = (float*)(ws + (3 << 20));
  float* mp0 = (float*)(ws + (4 << 20));
  float* mp1 = (float*)(ws + (5 << 20));
  ushort_t* wijf = (ushort_t*)(ws + (6 << 20));
  ushort_t* we2f = wijf + 32768;
  ushort_t* wh1f = we2f + 16384;
  ushort_t* wh2f = wh1f + 32768;

  prep_w<<<384, 256, 0, stream>>>(W_e1, W_e2, W_h1, W_h2, wijf, we2f, wh1f, wh2f);
  h0_proj<<<128, 256, 0, stream>>>(fres, W_emb, wijf, hA, tib, tjf);

  edge_kernel<<<2048, 256, 0, stream>>>(tib, tjf, coords, we2f, W_e1, b_e1, b_e2, W_inf, b_inf, mp0, mp1);
  node_kernel<<<128, 256, 0, stream>>>(hA, mp0, mp1, wh1f, b_h1, wh2f, b_h2, wijf, hB, tib, tjf, 1);

  edge_kernel<<<2048, 256, 0, stream>>>(tib, tjf, coords, we2f, W_e1, b_e1, b_e2, W_inf, b_inf, mp0, mp1);
  node_kernel<<<128, 256, 0, stream>>>(hB, mp0, mp1, wh1f, b_h1, wh2f, b_h2, wijf, out, tib, tjf, 0);
}